// Round 26
// baseline (151.747 us; speedup 1.0000x reference)
//
#include <hip/hip_runtime.h>
#include <cstdint>

#define BATCH 2
#define CCH 128
#define H2 64
#define NP 4096      /* 64*64 patches */
#define H1 128
#define YPB (CCH*H1*H1) /* 2097152 per batch */

typedef __attribute__((ext_vector_type(8))) short bf16x8;
typedef __attribute__((ext_vector_type(4))) float f32x4;

__device__ __forceinline__ uint16_t f2bf(float v) {
    uint32_t u = __float_as_uint(v);
    u = (u + 0x7FFFu + ((u >> 16) & 1u)) >> 16;
    return (uint16_t)u;
}

// ---------------- K1 v2: mask patch test + ordered compaction, 16 waves ------
__global__ void __launch_bounds__(1024) k1_compact(const float* __restrict__ mask,
                                                   int* __restrict__ cnt,
                                                   int* __restrict__ idx)
{
    __shared__ int widx[16][256];
    __shared__ int wcnt[16];
    __shared__ int woff[16];
    int b    = blockIdx.x;
    int t    = threadIdx.x;
    int lane = t & 63;
    int w    = t >> 6;             // 0..15
    const float* mb = mask + b * (H2*H2);
    int count = 0;
    #pragma unroll
    for (int it = 0; it < 4; ++it) {
        int p = w*256 + it*64 + lane;
        int ph = p >> 6, pw = p & 63;
        float s = 0.f;
        #pragma unroll
        for (int dh = -1; dh <= 1; ++dh) {
            int r = ph + dh;
            if ((unsigned)r < (unsigned)H2) {
                #pragma unroll
                for (int dw = -1; dw <= 1; ++dw) {
                    int c = pw + dw;
                    if ((unsigned)c < (unsigned)H2) s += mb[r*H2 + c];
                }
            }
        }
        bool flag = (s == 0.0f);
        unsigned long long m = __ballot(flag);
        int pre = __popcll(m & ((1ull << lane) - 1ull));
        if (flag) widx[w][count + pre] = p;
        count += __popcll(m);
    }
    if (lane == 0) wcnt[w] = count;
    __syncthreads();
    if (t == 0) {
        int acc = 0;
        #pragma unroll
        for (int i = 0; i < 16; ++i) { woff[i] = acc; acc += wcnt[i]; }
        cnt[b] = acc;
    }
    __syncthreads();
    int base = b*NP + woff[w];
    int n = wcnt[w];
    for (int i = lane; i < n; i += 64)
        idx[base + i] = widx[w][i];
}

// ---------------- K2: 1/max(||patch_q||, 1e-4) for selected q ----------------
__global__ void k2_norms(const float* __restrict__ x2, const int* __restrict__ cnt,
                         const int* __restrict__ idx, float* __restrict__ rnorm)
{
    int cnt0 = cnt[0], cnt1 = cnt[1];
    int total = cnt0 + cnt1;
    int lane = threadIdx.x;
    for (int item = blockIdx.x; item < total; item += gridDim.x) {
        int b, j;
        if (item < cnt0) { b = 0; j = item; } else { b = 1; j = item - cnt0; }
        int p = idx[b*NP + j];
        int qh = p >> 6, qw = p & 63;
        const float* xb = x2 + (size_t)b * CCH * H2 * H2;
        float s = 0.f;
        for (int c = lane; c < CCH; c += 64) {
            const float* xc = xb + (size_t)c * H2 * H2;
            #pragma unroll
            for (int dh = -1; dh <= 1; ++dh) {
                int r = qh + dh;
                if ((unsigned)r < (unsigned)H2) {
                    #pragma unroll
                    for (int dw = -1; dw <= 1; ++dw) {
                        int cc = qw + dw;
                        if ((unsigned)cc < (unsigned)H2) { float v = xc[r*H2 + cc]; s += v*v; }
                    }
                }
            }
        }
        #pragma unroll
        for (int off = 32; off > 0; off >>= 1) s += __shfl_down(s, off, 64);
        if (lane == 0) rnorm[b*NP + j] = 1.0f / fmaxf(sqrtf(s), 1e-4f);
    }
}

// ---------------- K3 v4: S[q,s] = <patch_s, patch_q> * rnorm_q ---------------
__global__ void __launch_bounds__(256) k3_scores(const float* __restrict__ x2,
    const int* __restrict__ cnt, const int* __restrict__ idx,
    const float* __restrict__ rnorm, float* __restrict__ S, int base, int CQ)
{
    __shared__ float f[9*CCH];
    __shared__ float psum[4][64];
    int tid  = threadIdx.x;
    int lane = tid & 63;
    int wv   = tid >> 6;            // 0..3 : c-chunk
    int cnt0 = cnt[0], cnt1 = cnt[1];
    int nb0 = min(max(cnt0 - base, 0), CQ);
    int nb1 = min(max(cnt1 - base, 0), CQ);
    long units = (long)(nb0 + nb1) * 64;
    for (long u = blockIdx.x; u < units; u += gridDim.x) {
        int item = (int)(u >> 6);
        int h    = (int)(u & 63);
        int b, jq;
        if (item < nb0) { b = 0; jq = item; } else { b = 1; jq = item - nb0; }
        int jg = base + jq;
        int p = idx[b*NP + jg];
        int qh = p >> 6, qw = p & 63;
        float rn = rnorm[b*NP + jg];
        const float* xb = x2 + (size_t)b * CCH * H2 * H2;
        for (int t2 = tid; t2 < 9*CCH; t2 += 256) {
            int k = t2 >> 7, c = t2 & 127;
            int dh = k / 3, dw = k % 3;
            int r = qh + dh - 1, cc = qw + dw - 1;
            float v = 0.f;
            if ((unsigned)r < (unsigned)H2 && (unsigned)cc < (unsigned)H2)
                v = xb[((size_t)c*H2 + r)*H2 + cc];
            f[t2] = v * rn;
        }
        __syncthreads();
        int c0 = wv * 32;
        float a0=0.f,a1=0.f,a2=0.f,a3=0.f,a4=0.f,a5=0.f,a6=0.f,a7=0.f;
        #pragma unroll
        for (int k = 0; k < 9; ++k) {
            int dh = k/3, dw = k%3;
            int rr = h + dh - 1;
            int cc = lane + dw - 1;
            if ((unsigned)rr < (unsigned)H2 && (unsigned)cc < (unsigned)H2) {
                const float* xp = xb + (size_t)c0*H2*H2 + (size_t)rr*H2 + cc;
                const float* fp = f + k*CCH + c0;
                #pragma unroll
                for (int c = 0; c < 32; c += 8) {
                    a0 += xp[(size_t)(c+0)*H2*H2] * fp[c+0];
                    a1 += xp[(size_t)(c+1)*H2*H2] * fp[c+1];
                    a2 += xp[(size_t)(c+2)*H2*H2] * fp[c+2];
                    a3 += xp[(size_t)(c+3)*H2*H2] * fp[c+3];
                    a4 += xp[(size_t)(c+4)*H2*H2] * fp[c+4];
                    a5 += xp[(size_t)(c+5)*H2*H2] * fp[c+5];
                    a6 += xp[(size_t)(c+6)*H2*H2] * fp[c+6];
                    a7 += xp[(size_t)(c+7)*H2*H2] * fp[c+7];
                }
            }
        }
        psum[wv][lane] = ((a0+a1)+(a2+a3)) + ((a4+a5)+(a6+a7));
        __syncthreads();
        if (wv == 0) {
            float sv = (psum[0][lane] + psum[1][lane])
                     + (psum[2][lane] + psum[3][lane]);
            S[((size_t)(b*CQ + jq))*NP + h*64 + lane] = sv;
        }
        __syncthreads();
    }
}

// ---------------- K3b: online softmax stats (init fused via flag) ------------
__global__ void k3b_stats(const float* __restrict__ S, const int* __restrict__ cnt,
                          float* __restrict__ M, float* __restrict__ D,
                          int base, int CQ, int init)
{
    int t = blockIdx.x*blockDim.x + threadIdx.x;
    if (t >= BATCH*NP) return;
    int b = t >> 12, s = t & (NP-1);
    int n = min(max(cnt[b] - base, 0), CQ);
    float m, d;
    if (init) { m = 0.f; d = (float)(NP - cnt[b]); }
    else {
        if (n == 0) return;
        m = M[t]; d = D[t];
    }
    for (int j = 0; j < n; ++j) {
        float l = 10.f * S[((size_t)(b*CQ + j))*NP + s];
        if (l > m) { d = d*__expf(m - l) + 1.f; m = l; }
        else       { d += __expf(l - m); }
    }
    M[t] = m; D[t] = d;
}

// ---------------- K5 v6: paste; x1 loads SCALARIZED via readfirstlane --------
// Per (j,co) the x1 addresses depend only on the patch qp (block-uniform);
// lanes differ only in an even/odd parity pick among 4 consecutive columns
// {2qw-1, 2qw, 2qw+1, 2qw+2} (clamped). Forcing qp into an SGPR makes every
// x1 address scalar -> s_load (the k6-weights mechanism), removing ~all of
// k5's 200M VMEM loads. Values and FMA order are BIT-IDENTICAL to v4.
#define TJ 32
__global__ void __launch_bounds__(128) k5_paste(const float* __restrict__ A,
    const int* __restrict__ cnt, const int* __restrict__ idx,
    const float* __restrict__ x1,
    const float* __restrict__ M, const float* __restrict__ D,
    float* __restrict__ y, int base, int CQ, int accumulate)
{
    __shared__ float sA[TJ][2][64];
    __shared__ int   sQ[TJ];
    int ow = threadIdx.x;          // 0..127
    int ck = blockIdx.x;           // 0..7 : co chunk of 16
    int oh = blockIdx.y;           // 0..127
    int b  = blockIdx.z;           // 0..1
    int n = min(max(cnt[b] - base, 0), CQ);

    if (n == 0) {
        if (!accumulate) {
            size_t obase = ((size_t)(b*CCH + ck*16)*H1 + oh)*H1 + ow;
            #pragma unroll
            for (int co = 0; co < 16; ++co) y[obase + (size_t)co*H1*H1] = 0.f;
        }
        return;
    }

    int ohp = oh & 1;
    int ih0 = (oh + 1) >> 1;
    int ihv0 = (ih0 <= 63);
    int ihv1 = (ih0 >= 1);
    int iw0 = (ow + 1) >> 1;
    int iwv0 = (iw0 <= 63);
    int iwv1 = (iw0 >= 1);
    int iwc0 = min(max(iw0, 0), 63);
    int iwc1 = min(max(iw0 - 1, 0), 63);
    bool odd = (ow & 1) != 0;

    float acc[16];
    #pragma unroll
    for (int o = 0; o < 16; ++o) acc[o] = 0.f;

    const float* x1c = x1 + ((size_t)(b*CCH + ck*16))*H1*H1;
    const float* Mb = M + b*NP;
    const float* Db = D + b*NP;

    for (int j0 = 0; j0 < n; j0 += TJ) {
        int m = min(TJ, n - j0);
        if (ow < m) sQ[ow] = idx[b*NP + base + j0 + ow];
        for (int u = ow; u < m*128; u += 128) {
            int j  = u >> 7;
            int s  = (u >> 6) & 1;
            int iw = u & 63;
            int ih = ih0 - s;
            int ihc = min(max(ih, 0), 63);
            float v = 0.f;
            if (s == 0 ? ihv0 : ihv1) {
                int scol = ihc*64 + iw;
                float sv = A[((size_t)(b*CQ + j0 + j))*NP + scol];
                v = __expf(10.f*sv - Mb[scol]) / Db[scol];
            }
            sA[j][s][iw] = v;
        }
        __syncthreads();
        for (int j = 0; j < m; ++j) {
            int qp = __builtin_amdgcn_readfirstlane(sQ[j]);   // block-uniform
            int qh = qp >> 6, qw = qp & 63;
            int rr0 = 2*qh - ohp;
            int rr1 = rr0 + 2;
            int cc0 = 2*qw - (ow & 1);          // per-lane parity only
            int cc1 = cc0 + 2;
            int rv0 = ihv0 && ((unsigned)rr0 < (unsigned)H1);
            int rv1 = ihv1 && ((unsigned)rr1 < (unsigned)H1);
            int cv0 = iwv0 && ((unsigned)cc0 < (unsigned)H1);
            int cv1 = iwv1 && ((unsigned)cc1 < (unsigned)H1);
            float w00 = (rv0 && cv0) ? sA[j][0][iwc0] : 0.f;
            float w01 = (rv0 && cv1) ? sA[j][0][iwc1] : 0.f;
            float w10 = (rv1 && cv0) ? sA[j][1][iwc0] : 0.f;
            float w11 = (rv1 && cv1) ? sA[j][1][iwc1] : 0.f;
            // scalar x1 addresses (all uniform): rows r0,r1; cols cA..cD
            int r0 = min(max(rr0, 0), H1-1) * H1;
            int r1 = min(max(rr1, 0), H1-1) * H1;
            int cA = max(2*qw - 1, 0);          // odd-lane col for cc0
            int cB = 2*qw;                      // even-lane col for cc0
            int cC = 2*qw + 1;                  // odd-lane col for cc1
            int cD = min(2*qw + 2, H1-1);       // even-lane col for cc1
            #pragma unroll
            for (int co = 0; co < 16; ++co) {
                const float* pc = x1c + (size_t)co*H1*H1;
                float xA0 = pc[r0 + cA], xB0 = pc[r0 + cB];
                float xC0 = pc[r0 + cC], xD0 = pc[r0 + cD];
                float xA1 = pc[r1 + cA], xB1 = pc[r1 + cB];
                float xC1 = pc[r1 + cC], xD1 = pc[r1 + cD];
                float x00 = odd ? xA0 : xB0;    // == pc[clamp(rr0)*H1 + clamp(cc0)]
                float x01 = odd ? xC0 : xD0;    // == pc[clamp(rr0)*H1 + clamp(cc1)]
                float x10 = odd ? xA1 : xB1;
                float x11 = odd ? xC1 : xD1;
                acc[co] += w00*x00 + w01*x01 + w10*x10 + w11*x11;
            }
        }
        __syncthreads();
    }
    size_t obase = ((size_t)(b*CCH + ck*16)*H1 + oh)*H1 + ow;
    #pragma unroll
    for (int co = 0; co < 16; ++co) {
        size_t oi = obase + (size_t)co*H1*H1;
        float v = 0.25f*acc[co];
        y[oi] = accumulate ? (y[oi] + v) : v;
    }
}

// ---------------- K_ybt: y -> channel-last bf16 (standalone, ~8us) -----------
__global__ void __launch_bounds__(128) k_ybt(const float* __restrict__ y,
                                             uint16_t* __restrict__ ybt)
{
    __shared__ uint16_t tile[128*130 + 2];   // [col][ch] padded (+2 u16/row)
    int row = blockIdx.x & 127;
    int b   = blockIdx.x >> 7;
    int col = threadIdx.x;
    const float* yb = y + (size_t)b*YPB + (size_t)row*H1;
    for (int c = 0; c < CCH; ++c) {
        float v = yb[(size_t)c*H1*H1 + col];
        tile[col*130 + c] = f2bf(v);
    }
    __syncthreads();
    uint32_t* dst = (uint32_t*)(ybt + ((size_t)(b*H1 + row))*H1*CCH);
    const uint32_t* tl = (const uint32_t*)tile;
    for (int i = threadIdx.x; i < H1*CCH/2; i += 128) {
        int cidx = i >> 6;          // col
        int chh  = i & 63;          // ch pair
        dst[i] = tl[cidx*65 + chh];
    }
}

// ---------------- K_wprep: W -> bf16 MFMA-fragment layout --------------------
__global__ void k_wprep(const float* __restrict__ fw0, const float* __restrict__ fw1,
                        const float* __restrict__ fw2, const float* __restrict__ fw3,
                        uint16_t* __restrict__ wbf)
{
    int kstep = blockIdx.x % 36;
    int g     = blockIdx.x / 36;
    const float* fw = (g==0)?fw0:(g==1)?fw1:(g==2)?fw2:fw3;
    int l  = threadIdx.x;
    int co = l & 15;
    int kg = l >> 4;
    int tap = kstep >> 2;
    int c0  = (kstep & 3) * 32;
    uint16_t* dst = wbf + ((size_t)(g*36 + kstep)*64 + l)*8;
    #pragma unroll
    for (int i = 0; i < 8; ++i) {
        int ch = c0 + kg*8 + i;
        dst[i] = f2bf(fw[((size_t)co*CCH + ch)*9 + tap]);
    }
}

// ---------------- K6 MFMA v2 (verified round 24): 2 rows per block -----------
__global__ void __launch_bounds__(256) k6_mfma(const uint16_t* __restrict__ ybt,
    const uint16_t* __restrict__ wbf,
    const float* __restrict__ fb0, const float* __restrict__ fb1,
    const float* __restrict__ fb2, const float* __restrict__ fb3,
    float* __restrict__ out)
{
    int t    = threadIdx.x;
    int lane = t & 63;
    int wv   = t >> 6;                 // 0..3
    int L    = blockIdx.x;             // 0..511
    int xcd  = L & 7;                  // measured %8 XCD round-robin
    int slot = L >> 3;                 // 0..63
    int b    = xcd >> 2;
    int band = xcd & 3;
    int g    = slot >> 4;              // 0..3
    int pr   = slot & 15;              // 0..15
    int oh0  = band*32 + pr*2;
    int oh1  = oh0 + 1;
    int r    = 1 << g;
    const float* fb = (g==0)?fb0:(g==1)?fb1:(g==2)?fb2:fb3;
    int n15 = lane & 15;
    int kg  = lane >> 4;
    int ow0 = wv * 32;                 // tiles at ow0 and ow0+16
    f32x4 a00 = {0.f,0.f,0.f,0.f};     // row0 tile0
    f32x4 a01 = {0.f,0.f,0.f,0.f};     // row0 tile1
    f32x4 a10 = {0.f,0.f,0.f,0.f};     // row1 tile0
    f32x4 a11 = {0.f,0.f,0.f,0.f};     // row1 tile1
    const uint16_t* wbase = wbf + (size_t)g*36*512 + lane*8;
    const uint16_t* ybase = ybt + (size_t)b*H1*H1*CCH;
    const bf16x8 zero = {0,0,0,0,0,0,0,0};
    for (int ks = 0; ks < 36; ++ks) {
        int tap = ks >> 2;
        int c0  = (ks & 3) * 32;
        int dr  = r*(tap/3 - 1);
        int rr0 = oh0 + dr;
        int rr1 = oh1 + dr;
        bool rok0 = (unsigned)rr0 < (unsigned)H1;
        bool rok1 = (unsigned)rr1 < (unsigned)H1;
        int rr0c = min(max(rr0, 0), H1-1);
        int rr1c = min(max(rr1, 0), H1-1);
        bf16x8 af = *(const bf16x8*)(wbase + (size_t)ks*512);
        int chb = c0 + kg*8;
        const uint16_t* yrow0 = ybase + (size_t)rr0c*H1*CCH;
        const uint16_t* yrow1 = ybase + (size_t)rr1c*H1*CCH;
        int cc0 = ow0 + n15 + r*(tap%3 - 1);
        int cc1 = cc0 + 16;
        bool c0ok = (unsigned)cc0 < (unsigned)H1;
        bool c1ok = (unsigned)cc1 < (unsigned)H1;
        int cc0c = min(max(cc0, 0), H1-1);
        int cc1c = min(max(cc1, 0), H1-1);
        bf16x8 b00 = *(const bf16x8*)(yrow0 + (size_t)cc0c*CCH + chb);
        bf16x8 b01 = *(const bf16x8*)(yrow0 + (size_t)cc1c*CCH + chb);
        bf16x8 b10 = *(const bf16x8*)(yrow1 + (size_t)cc0c*CCH + chb);
        bf16x8 b11 = *(const bf16x8*)(yrow1 + (size_t)cc1c*CCH + chb);
        if (!(rok0 && c0ok)) b00 = zero;
        if (!(rok0 && c1ok)) b01 = zero;
        if (!(rok1 && c0ok)) b10 = zero;
        if (!(rok1 && c1ok)) b11 = zero;
        a00 = __builtin_amdgcn_mfma_f32_16x16x32_bf16(af, b00, a00, 0, 0, 0);
        a01 = __builtin_amdgcn_mfma_f32_16x16x32_bf16(af, b01, a01, 0, 0, 0);
        a10 = __builtin_amdgcn_mfma_f32_16x16x32_bf16(af, b10, a10, 0, 0, 0);
        a11 = __builtin_amdgcn_mfma_f32_16x16x32_bf16(af, b11, a11, 0, 0, 0);
    }
    #pragma unroll
    for (int j = 0; j < 4; ++j) {
        int co = kg*4 + j;
        float bias = fb[co];
        size_t r0 = ((size_t)(b*64 + g*16 + co)*H1 + oh0)*H1 + ow0 + n15;
        size_t r1 = ((size_t)(b*64 + g*16 + co)*H1 + oh1)*H1 + ow0 + n15;
        out[r0]      = fmaxf(a00[j] + bias, 0.f);
        out[r0 + 16] = fmaxf(a01[j] + bias, 0.f);
        out[r1]      = fmaxf(a10[j] + bias, 0.f);
        out[r1 + 16] = fmaxf(a11[j] + bias, 0.f);
    }
}

extern "C" void kernel_launch(void* const* d_in, const int* in_sizes, int n_in,
                              void* d_out, int out_size, void* d_ws, size_t ws_size,
                              hipStream_t stream)
{
    const float* x1   = (const float*)d_in[0];
    const float* x2   = (const float*)d_in[1];
    const float* mask = (const float*)d_in[2];
    const float* fw0 = (const float*)d_in[3];
    const float* fb0 = (const float*)d_in[4];
    const float* fw1 = (const float*)d_in[5];
    const float* fb1 = (const float*)d_in[6];
    const float* fw2 = (const float*)d_in[7];
    const float* fb2 = (const float*)d_in[8];
    const float* fw3 = (const float*)d_in[9];
    const float* fb3 = (const float*)d_in[10];
    float* out = (float*)d_out;
    char* ws = (char*)d_ws;

    size_t off = 0;
    auto alloc = [&](size_t bytes) { size_t o = off; off += (bytes + 255) & ~(size_t)255; return o; };
    size_t cnt_off = alloc(BATCH*sizeof(int));
    size_t idx_off = alloc((size_t)BATCH*NP*sizeof(int));
    size_t rn_off  = alloc((size_t)BATCH*NP*sizeof(float));
    size_t M_off   = alloc((size_t)BATCH*NP*sizeof(float));
    size_t D_off   = alloc((size_t)BATCH*NP*sizeof(float));
    size_t y_off   = alloc((size_t)BATCH*YPB*sizeof(float));
    size_t ybt_off = alloc((size_t)BATCH*H1*H1*CCH*sizeof(uint16_t));
    size_t wbf_off = alloc((size_t)4*36*512*sizeof(uint16_t));
    size_t remain = (ws_size > off) ? (ws_size - off) : 0;
    int CQ = (int)(remain / ((size_t)BATCH*NP*sizeof(float)));
    if (CQ > NP) CQ = NP;
    if (CQ < 1) CQ = 1;
    size_t S_off = off;
    int NCH = (NP + CQ - 1) / CQ;

    int* cnt   = (int*)(ws + cnt_off);
    int* idx   = (int*)(ws + idx_off);
    float* rnm = (float*)(ws + rn_off);
    float* Mv  = (float*)(ws + M_off);
    float* Dv  = (float*)(ws + D_off);
    float* y   = (float*)(ws + y_off);
    uint16_t* ybt = (uint16_t*)(ws + ybt_off);
    uint16_t* wbf = (uint16_t*)(ws + wbf_off);
    float* S   = (float*)(ws + S_off);

    k1_compact<<<BATCH, 1024, 0, stream>>>(mask, cnt, idx);
    k2_norms<<<256, 64, 0, stream>>>(x2, cnt, idx, rnm);
    k_wprep<<<4*36, 64, 0, stream>>>(fw0, fw1, fw2, fw3, wbf);
    // loop 1 (stats), DESCENDING so chunk 0's scores survive in S.
    // ch>0 chunks are empty for realistic masks: launch them narrow (512
    // blocks, grid-stride keeps pathological masks correct).
    for (int ch = NCH - 1; ch >= 0; --ch) {
        k3_scores<<<(ch == 0 ? 2048 : 512), 256, 0, stream>>>(x2, cnt, idx, rnm, S,
                                                              ch*CQ, CQ);
        k3b_stats<<<(BATCH*NP+255)/256, 256, 0, stream>>>(S, cnt, Mv, Dv, ch*CQ, CQ,
                                                          ch == NCH - 1 ? 1 : 0);
    }
    // loop 2 (normalize-in-staging + paste); ch0 reuses S from loop 1.
    for (int ch = 0; ch < NCH; ++ch) {
        if (ch > 0)
            k3_scores<<<512, 256, 0, stream>>>(x2, cnt, idx, rnm, S, ch*CQ, CQ);
        k5_paste<<<dim3(8, H1, BATCH), 128, 0, stream>>>(S, cnt, idx, x1, Mv, Dv, y,
                                                         ch*CQ, CQ, ch > 0 ? 1 : 0);
    }
    // final conv: standalone channel-last bf16 convert + MFMA
    k_ybt<<<BATCH*H1, 128, 0, stream>>>(y, ybt);
    k6_mfma<<<512, 256, 0, stream>>>(ybt, wbf, fb0, fb1, fb2, fb3, out);
}

// Round 27
// 127.612 us; speedup vs baseline: 1.1891x; 1.1891x over previous
//
#include <hip/hip_runtime.h>
#include <cstdint>

#define BATCH 2
#define CCH 128
#define H2 64
#define NP 4096      /* 64*64 patches */
#define H1 128
#define YPB (CCH*H1*H1) /* 2097152 per batch */

typedef __attribute__((ext_vector_type(8))) short bf16x8;
typedef __attribute__((ext_vector_type(4))) float f32x4;

__device__ __forceinline__ uint16_t f2bf(float v) {
    uint32_t u = __float_as_uint(v);
    u = (u + 0x7FFFu + ((u >> 16) & 1u)) >> 16;
    return (uint16_t)u;
}

// ---------------- K1 v2: mask patch test + ordered compaction, 16 waves ------
__global__ void __launch_bounds__(1024) k1_compact(const float* __restrict__ mask,
                                                   int* __restrict__ cnt,
                                                   int* __restrict__ idx)
{
    __shared__ int widx[16][256];
    __shared__ int wcnt[16];
    __shared__ int woff[16];
    int b    = blockIdx.x;
    int t    = threadIdx.x;
    int lane = t & 63;
    int w    = t >> 6;             // 0..15
    const float* mb = mask + b * (H2*H2);
    int count = 0;
    #pragma unroll
    for (int it = 0; it < 4; ++it) {
        int p = w*256 + it*64 + lane;
        int ph = p >> 6, pw = p & 63;
        float s = 0.f;
        #pragma unroll
        for (int dh = -1; dh <= 1; ++dh) {
            int r = ph + dh;
            if ((unsigned)r < (unsigned)H2) {
                #pragma unroll
                for (int dw = -1; dw <= 1; ++dw) {
                    int c = pw + dw;
                    if ((unsigned)c < (unsigned)H2) s += mb[r*H2 + c];
                }
            }
        }
        bool flag = (s == 0.0f);
        unsigned long long m = __ballot(flag);
        int pre = __popcll(m & ((1ull << lane) - 1ull));
        if (flag) widx[w][count + pre] = p;
        count += __popcll(m);
    }
    if (lane == 0) wcnt[w] = count;
    __syncthreads();
    if (t == 0) {
        int acc = 0;
        #pragma unroll
        for (int i = 0; i < 16; ++i) { woff[i] = acc; acc += wcnt[i]; }
        cnt[b] = acc;
    }
    __syncthreads();
    int base = b*NP + woff[w];
    int n = wcnt[w];
    for (int i = lane; i < n; i += 64)
        idx[base + i] = widx[w][i];
}

// ---------------- K2: 1/max(||patch_q||, 1e-4) for selected q ----------------
__global__ void k2_norms(const float* __restrict__ x2, const int* __restrict__ cnt,
                         const int* __restrict__ idx, float* __restrict__ rnorm)
{
    int cnt0 = cnt[0], cnt1 = cnt[1];
    int total = cnt0 + cnt1;
    int lane = threadIdx.x;
    for (int item = blockIdx.x; item < total; item += gridDim.x) {
        int b, j;
        if (item < cnt0) { b = 0; j = item; } else { b = 1; j = item - cnt0; }
        int p = idx[b*NP + j];
        int qh = p >> 6, qw = p & 63;
        const float* xb = x2 + (size_t)b * CCH * H2 * H2;
        float s = 0.f;
        for (int c = lane; c < CCH; c += 64) {
            const float* xc = xb + (size_t)c * H2 * H2;
            #pragma unroll
            for (int dh = -1; dh <= 1; ++dh) {
                int r = qh + dh;
                if ((unsigned)r < (unsigned)H2) {
                    #pragma unroll
                    for (int dw = -1; dw <= 1; ++dw) {
                        int cc = qw + dw;
                        if ((unsigned)cc < (unsigned)H2) { float v = xc[r*H2 + cc]; s += v*v; }
                    }
                }
            }
        }
        #pragma unroll
        for (int off = 32; off > 0; off >>= 1) s += __shfl_down(s, off, 64);
        if (lane == 0) rnorm[b*NP + j] = 1.0f / fmaxf(sqrtf(s), 1e-4f);
    }
}

// ---------------- K3 v4: S[q,s] = <patch_s, patch_q> * rnorm_q ---------------
__global__ void __launch_bounds__(256) k3_scores(const float* __restrict__ x2,
    const int* __restrict__ cnt, const int* __restrict__ idx,
    const float* __restrict__ rnorm, float* __restrict__ S, int base, int CQ)
{
    __shared__ float f[9*CCH];
    __shared__ float psum[4][64];
    int tid  = threadIdx.x;
    int lane = tid & 63;
    int wv   = tid >> 6;            // 0..3 : c-chunk
    int cnt0 = cnt[0], cnt1 = cnt[1];
    int nb0 = min(max(cnt0 - base, 0), CQ);
    int nb1 = min(max(cnt1 - base, 0), CQ);
    long units = (long)(nb0 + nb1) * 64;
    for (long u = blockIdx.x; u < units; u += gridDim.x) {
        int item = (int)(u >> 6);
        int h    = (int)(u & 63);
        int b, jq;
        if (item < nb0) { b = 0; jq = item; } else { b = 1; jq = item - nb0; }
        int jg = base + jq;
        int p = idx[b*NP + jg];
        int qh = p >> 6, qw = p & 63;
        float rn = rnorm[b*NP + jg];
        const float* xb = x2 + (size_t)b * CCH * H2 * H2;
        for (int t2 = tid; t2 < 9*CCH; t2 += 256) {
            int k = t2 >> 7, c = t2 & 127;
            int dh = k / 3, dw = k % 3;
            int r = qh + dh - 1, cc = qw + dw - 1;
            float v = 0.f;
            if ((unsigned)r < (unsigned)H2 && (unsigned)cc < (unsigned)H2)
                v = xb[((size_t)c*H2 + r)*H2 + cc];
            f[t2] = v * rn;
        }
        __syncthreads();
        int c0 = wv * 32;
        float a0=0.f,a1=0.f,a2=0.f,a3=0.f,a4=0.f,a5=0.f,a6=0.f,a7=0.f;
        #pragma unroll
        for (int k = 0; k < 9; ++k) {
            int dh = k/3, dw = k%3;
            int rr = h + dh - 1;
            int cc = lane + dw - 1;
            if ((unsigned)rr < (unsigned)H2 && (unsigned)cc < (unsigned)H2) {
                const float* xp = xb + (size_t)c0*H2*H2 + (size_t)rr*H2 + cc;
                const float* fp = f + k*CCH + c0;
                #pragma unroll
                for (int c = 0; c < 32; c += 8) {
                    a0 += xp[(size_t)(c+0)*H2*H2] * fp[c+0];
                    a1 += xp[(size_t)(c+1)*H2*H2] * fp[c+1];
                    a2 += xp[(size_t)(c+2)*H2*H2] * fp[c+2];
                    a3 += xp[(size_t)(c+3)*H2*H2] * fp[c+3];
                    a4 += xp[(size_t)(c+4)*H2*H2] * fp[c+4];
                    a5 += xp[(size_t)(c+5)*H2*H2] * fp[c+5];
                    a6 += xp[(size_t)(c+6)*H2*H2] * fp[c+6];
                    a7 += xp[(size_t)(c+7)*H2*H2] * fp[c+7];
                }
            }
        }
        psum[wv][lane] = ((a0+a1)+(a2+a3)) + ((a4+a5)+(a6+a7));
        __syncthreads();
        if (wv == 0) {
            float sv = (psum[0][lane] + psum[1][lane])
                     + (psum[2][lane] + psum[3][lane]);
            S[((size_t)(b*CQ + jq))*NP + h*64 + lane] = sv;
        }
        __syncthreads();
    }
}

// ---------------- K3b: online softmax stats (init fused via flag) ------------
__global__ void k3b_stats(const float* __restrict__ S, const int* __restrict__ cnt,
                          float* __restrict__ M, float* __restrict__ D,
                          int base, int CQ, int init)
{
    int t = blockIdx.x*blockDim.x + threadIdx.x;
    if (t >= BATCH*NP) return;
    int b = t >> 12, s = t & (NP-1);
    int n = min(max(cnt[b] - base, 0), CQ);
    float m, d;
    if (init) { m = 0.f; d = (float)(NP - cnt[b]); }
    else {
        if (n == 0) return;
        m = M[t]; d = D[t];
    }
    for (int j = 0; j < n; ++j) {
        float l = 10.f * S[((size_t)(b*CQ + j))*NP + s];
        if (l > m) { d = d*__expf(m - l) + 1.f; m = l; }
        else       { d += __expf(l - m); }
    }
    M[t] = m; D[t] = d;
}

// ---------------- K5 v4 (RESTORED: proven ~31us rounds 13-25) ----------------
// (v6 scalarization REVERTED: 8 scattered s_loads + 4 selects per (j,co)
// serialized on the single SMEM port -> 31us became 67-84us. Scalar fetch
// only wins when wide/sequential, like k6's weight stream.)
#define TJ 32
__global__ void __launch_bounds__(128) k5_paste(const float* __restrict__ A,
    const int* __restrict__ cnt, const int* __restrict__ idx,
    const float* __restrict__ x1,
    const float* __restrict__ M, const float* __restrict__ D,
    float* __restrict__ y, int base, int CQ, int accumulate)
{
    __shared__ float sA[TJ][2][64];
    __shared__ int   sQ[TJ];
    int ow = threadIdx.x;          // 0..127
    int ck = blockIdx.x;           // 0..7 : co chunk of 16
    int oh = blockIdx.y;           // 0..127
    int b  = blockIdx.z;           // 0..1
    int n = min(max(cnt[b] - base, 0), CQ);

    if (n == 0) {
        if (!accumulate) {
            size_t obase = ((size_t)(b*CCH + ck*16)*H1 + oh)*H1 + ow;
            #pragma unroll
            for (int co = 0; co < 16; ++co) y[obase + (size_t)co*H1*H1] = 0.f;
        }
        return;
    }

    int ohp = oh & 1;
    int ih0 = (oh + 1) >> 1;
    int ihv0 = (ih0 <= 63);
    int ihv1 = (ih0 >= 1);
    int iw0 = (ow + 1) >> 1;
    int iwv0 = (iw0 <= 63);
    int iwv1 = (iw0 >= 1);

    float acc[16];
    #pragma unroll
    for (int o = 0; o < 16; ++o) acc[o] = 0.f;

    const float* x1c = x1 + ((size_t)(b*CCH + ck*16))*H1*H1;
    const float* Mb = M + b*NP;
    const float* Db = D + b*NP;

    for (int j0 = 0; j0 < n; j0 += TJ) {
        int m = min(TJ, n - j0);
        if (ow < m) sQ[ow] = idx[b*NP + base + j0 + ow];
        for (int u = ow; u < m*128; u += 128) {
            int j  = u >> 7;
            int s  = (u >> 6) & 1;
            int iw = u & 63;
            int ih = ih0 - s;
            int ihc = min(max(ih, 0), 63);
            float v = 0.f;
            if (s == 0 ? ihv0 : ihv1) {
                int scol = ihc*64 + iw;
                float sv = A[((size_t)(b*CQ + j0 + j))*NP + scol];
                v = __expf(10.f*sv - Mb[scol]) / Db[scol];
            }
            sA[j][s][iw] = v;
        }
        __syncthreads();
        for (int j = 0; j < m; ++j) {
            int qp = sQ[j];
            int qh = qp >> 6, qw = qp & 63;
            int rr0 = 2*qh - ohp;
            int rr1 = rr0 + 2;
            int cc0 = 2*qw - (ow & 1);
            int cc1 = cc0 + 2;
            int rv0 = ihv0 && ((unsigned)rr0 < (unsigned)H1);
            int rv1 = ihv1 && ((unsigned)rr1 < (unsigned)H1);
            int cv0 = iwv0 && ((unsigned)cc0 < (unsigned)H1);
            int cv1 = iwv1 && ((unsigned)cc1 < (unsigned)H1);
            int iwc0 = min(max(iw0, 0), 63);
            int iwc1 = min(max(iw0 - 1, 0), 63);
            float w00 = (rv0 && cv0) ? sA[j][0][iwc0] : 0.f;
            float w01 = (rv0 && cv1) ? sA[j][0][iwc1] : 0.f;
            float w10 = (rv1 && cv0) ? sA[j][1][iwc0] : 0.f;
            float w11 = (rv1 && cv1) ? sA[j][1][iwc1] : 0.f;
            int r0c = min(max(rr0, 0), H1-1) * H1;
            int r1c = min(max(rr1, 0), H1-1) * H1;
            int c0c = min(max(cc0, 0), H1-1);
            int c1c = min(max(cc1, 0), H1-1);
            int off00 = r0c + c0c;
            int off01 = r0c + c1c;
            int off10 = r1c + c0c;
            int off11 = r1c + c1c;
            #pragma unroll
            for (int co = 0; co < 16; ++co) {
                const float* pc = x1c + (size_t)co*H1*H1;
                acc[co] += w00*pc[off00] + w01*pc[off01]
                         + w10*pc[off10] + w11*pc[off11];
            }
        }
        __syncthreads();
    }
    size_t obase = ((size_t)(b*CCH + ck*16)*H1 + oh)*H1 + ow;
    #pragma unroll
    for (int co = 0; co < 16; ++co) {
        size_t oi = obase + (size_t)co*H1*H1;
        float v = 0.25f*acc[co];
        y[oi] = accumulate ? (y[oi] + v) : v;
    }
}

// ---------------- K_ybt: y -> channel-last bf16 (standalone, ~8us) -----------
__global__ void __launch_bounds__(128) k_ybt(const float* __restrict__ y,
                                             uint16_t* __restrict__ ybt)
{
    __shared__ uint16_t tile[128*130 + 2];   // [col][ch] padded (+2 u16/row)
    int row = blockIdx.x & 127;
    int b   = blockIdx.x >> 7;
    int col = threadIdx.x;
    const float* yb = y + (size_t)b*YPB + (size_t)row*H1;
    for (int c = 0; c < CCH; ++c) {
        float v = yb[(size_t)c*H1*H1 + col];
        tile[col*130 + c] = f2bf(v);
    }
    __syncthreads();
    uint32_t* dst = (uint32_t*)(ybt + ((size_t)(b*H1 + row))*H1*CCH);
    const uint32_t* tl = (const uint32_t*)tile;
    for (int i = threadIdx.x; i < H1*CCH/2; i += 128) {
        int cidx = i >> 6;          // col
        int chh  = i & 63;          // ch pair
        dst[i] = tl[cidx*65 + chh];
    }
}

// ---------------- K_wprep: W -> bf16 MFMA-fragment layout --------------------
__global__ void k_wprep(const float* __restrict__ fw0, const float* __restrict__ fw1,
                        const float* __restrict__ fw2, const float* __restrict__ fw3,
                        uint16_t* __restrict__ wbf)
{
    int kstep = blockIdx.x % 36;
    int g     = blockIdx.x / 36;
    const float* fw = (g==0)?fw0:(g==1)?fw1:(g==2)?fw2:fw3;
    int l  = threadIdx.x;
    int co = l & 15;
    int kg = l >> 4;
    int tap = kstep >> 2;
    int c0  = (kstep & 3) * 32;
    uint16_t* dst = wbf + ((size_t)(g*36 + kstep)*64 + l)*8;
    #pragma unroll
    for (int i = 0; i < 8; ++i) {
        int ch = c0 + kg*8 + i;
        dst[i] = f2bf(fw[((size_t)co*CCH + ch)*9 + tap]);
    }
}

// ---------------- K6 MFMA v2 (verified round 24): 2 rows per block -----------
__global__ void __launch_bounds__(256) k6_mfma(const uint16_t* __restrict__ ybt,
    const uint16_t* __restrict__ wbf,
    const float* __restrict__ fb0, const float* __restrict__ fb1,
    const float* __restrict__ fb2, const float* __restrict__ fb3,
    float* __restrict__ out)
{
    int t    = threadIdx.x;
    int lane = t & 63;
    int wv   = t >> 6;                 // 0..3
    int L    = blockIdx.x;             // 0..511
    int xcd  = L & 7;                  // measured %8 XCD round-robin
    int slot = L >> 3;                 // 0..63
    int b    = xcd >> 2;
    int band = xcd & 3;
    int g    = slot >> 4;              // 0..3
    int pr   = slot & 15;              // 0..15
    int oh0  = band*32 + pr*2;
    int oh1  = oh0 + 1;
    int r    = 1 << g;
    const float* fb = (g==0)?fb0:(g==1)?fb1:(g==2)?fb2:fb3;
    int n15 = lane & 15;
    int kg  = lane >> 4;
    int ow0 = wv * 32;                 // tiles at ow0 and ow0+16
    f32x4 a00 = {0.f,0.f,0.f,0.f};     // row0 tile0
    f32x4 a01 = {0.f,0.f,0.f,0.f};     // row0 tile1
    f32x4 a10 = {0.f,0.f,0.f,0.f};     // row1 tile0
    f32x4 a11 = {0.f,0.f,0.f,0.f};     // row1 tile1
    const uint16_t* wbase = wbf + (size_t)g*36*512 + lane*8;
    const uint16_t* ybase = ybt + (size_t)b*H1*H1*CCH;
    const bf16x8 zero = {0,0,0,0,0,0,0,0};
    for (int ks = 0; ks < 36; ++ks) {
        int tap = ks >> 2;
        int c0  = (ks & 3) * 32;
        int dr  = r*(tap/3 - 1);
        int rr0 = oh0 + dr;
        int rr1 = oh1 + dr;
        bool rok0 = (unsigned)rr0 < (unsigned)H1;
        bool rok1 = (unsigned)rr1 < (unsigned)H1;
        int rr0c = min(max(rr0, 0), H1-1);
        int rr1c = min(max(rr1, 0), H1-1);
        bf16x8 af = *(const bf16x8*)(wbase + (size_t)ks*512);
        int chb = c0 + kg*8;
        const uint16_t* yrow0 = ybase + (size_t)rr0c*H1*CCH;
        const uint16_t* yrow1 = ybase + (size_t)rr1c*H1*CCH;
        int cc0 = ow0 + n15 + r*(tap%3 - 1);
        int cc1 = cc0 + 16;
        bool c0ok = (unsigned)cc0 < (unsigned)H1;
        bool c1ok = (unsigned)cc1 < (unsigned)H1;
        int cc0c = min(max(cc0, 0), H1-1);
        int cc1c = min(max(cc1, 0), H1-1);
        bf16x8 b00 = *(const bf16x8*)(yrow0 + (size_t)cc0c*CCH + chb);
        bf16x8 b01 = *(const bf16x8*)(yrow0 + (size_t)cc1c*CCH + chb);
        bf16x8 b10 = *(const bf16x8*)(yrow1 + (size_t)cc0c*CCH + chb);
        bf16x8 b11 = *(const bf16x8*)(yrow1 + (size_t)cc1c*CCH + chb);
        if (!(rok0 && c0ok)) b00 = zero;
        if (!(rok0 && c1ok)) b01 = zero;
        if (!(rok1 && c0ok)) b10 = zero;
        if (!(rok1 && c1ok)) b11 = zero;
        a00 = __builtin_amdgcn_mfma_f32_16x16x32_bf16(af, b00, a00, 0, 0, 0);
        a01 = __builtin_amdgcn_mfma_f32_16x16x32_bf16(af, b01, a01, 0, 0, 0);
        a10 = __builtin_amdgcn_mfma_f32_16x16x32_bf16(af, b10, a10, 0, 0, 0);
        a11 = __builtin_amdgcn_mfma_f32_16x16x32_bf16(af, b11, a11, 0, 0, 0);
    }
    #pragma unroll
    for (int j = 0; j < 4; ++j) {
        int co = kg*4 + j;
        float bias = fb[co];
        size_t r0 = ((size_t)(b*64 + g*16 + co)*H1 + oh0)*H1 + ow0 + n15;
        size_t r1 = ((size_t)(b*64 + g*16 + co)*H1 + oh1)*H1 + ow0 + n15;
        out[r0]      = fmaxf(a00[j] + bias, 0.f);
        out[r0 + 16] = fmaxf(a01[j] + bias, 0.f);
        out[r1]      = fmaxf(a10[j] + bias, 0.f);
        out[r1 + 16] = fmaxf(a11[j] + bias, 0.f);
    }
}

extern "C" void kernel_launch(void* const* d_in, const int* in_sizes, int n_in,
                              void* d_out, int out_size, void* d_ws, size_t ws_size,
                              hipStream_t stream)
{
    const float* x1   = (const float*)d_in[0];
    const float* x2   = (const float*)d_in[1];
    const float* mask = (const float*)d_in[2];
    const float* fw0 = (const float*)d_in[3];
    const float* fb0 = (const float*)d_in[4];
    const float* fw1 = (const float*)d_in[5];
    const float* fb1 = (const float*)d_in[6];
    const float* fw2 = (const float*)d_in[7];
    const float* fb2 = (const float*)d_in[8];
    const float* fw3 = (const float*)d_in[9];
    const float* fb3 = (const float*)d_in[10];
    float* out = (float*)d_out;
    char* ws = (char*)d_ws;

    size_t off = 0;
    auto alloc = [&](size_t bytes) { size_t o = off; off += (bytes + 255) & ~(size_t)255; return o; };
    size_t cnt_off = alloc(BATCH*sizeof(int));
    size_t idx_off = alloc((size_t)BATCH*NP*sizeof(int));
    size_t rn_off  = alloc((size_t)BATCH*NP*sizeof(float));
    size_t M_off   = alloc((size_t)BATCH*NP*sizeof(float));
    size_t D_off   = alloc((size_t)BATCH*NP*sizeof(float));
    size_t y_off   = alloc((size_t)BATCH*YPB*sizeof(float));
    size_t ybt_off = alloc((size_t)BATCH*H1*H1*CCH*sizeof(uint16_t));
    size_t wbf_off = alloc((size_t)4*36*512*sizeof(uint16_t));
    size_t remain = (ws_size > off) ? (ws_size - off) : 0;
    int CQ = (int)(remain / ((size_t)BATCH*NP*sizeof(float)));
    if (CQ > NP) CQ = NP;
    if (CQ < 1) CQ = 1;
    size_t S_off = off;
    int NCH = (NP + CQ - 1) / CQ;

    int* cnt   = (int*)(ws + cnt_off);
    int* idx   = (int*)(ws + idx_off);
    float* rnm = (float*)(ws + rn_off);
    float* Mv  = (float*)(ws + M_off);
    float* Dv  = (float*)(ws + D_off);
    float* y   = (float*)(ws + y_off);
    uint16_t* ybt = (uint16_t*)(ws + ybt_off);
    uint16_t* wbf = (uint16_t*)(ws + wbf_off);
    float* S   = (float*)(ws + S_off);

    k1_compact<<<BATCH, 1024, 0, stream>>>(mask, cnt, idx);
    k2_norms<<<256, 64, 0, stream>>>(x2, cnt, idx, rnm);
    k_wprep<<<4*36, 64, 0, stream>>>(fw0, fw1, fw2, fw3, wbf);
    // loop 1 (stats), DESCENDING so chunk 0's scores survive in S.
    // ch>0 chunks are empty for realistic masks: launch them narrow (512
    // blocks, grid-stride keeps pathological masks correct).
    for (int ch = NCH - 1; ch >= 0; --ch) {
        k3_scores<<<(ch == 0 ? 2048 : 512), 256, 0, stream>>>(x2, cnt, idx, rnm, S,
                                                              ch*CQ, CQ);
        k3b_stats<<<(BATCH*NP+255)/256, 256, 0, stream>>>(S, cnt, Mv, Dv, ch*CQ, CQ,
                                                          ch == NCH - 1 ? 1 : 0);
    }
    // loop 2 (normalize-in-staging + paste); ch0 reuses S from loop 1.
    for (int ch = 0; ch < NCH; ++ch) {
        if (ch > 0)
            k3_scores<<<512, 256, 0, stream>>>(x2, cnt, idx, rnm, S, ch*CQ, CQ);
        k5_paste<<<dim3(8, H1, BATCH), 128, 0, stream>>>(S, cnt, idx, x1, Mv, Dv, y,
                                                         ch*CQ, CQ, ch > 0 ? 1 : 0);
    }
    // final conv: standalone channel-last bf16 convert + MFMA
    k_ybt<<<BATCH*H1, 128, 0, stream>>>(y, ybt);
    k6_mfma<<<512, 256, 0, stream>>>(ybt, wbf, fb0, fb1, fb2, fb3, out);
}